// Round 1
// baseline (1493.584 us; speedup 1.0000x reference)
//
#include <hip/hip_runtime.h>

#define NADDR 400000
#define NTX   400000
#define NEDGE 1500000
#define FIN   64
#define HID   32

static inline int cdiv_host(long a, int b) { return (int)((a + b - 1) / b); }

// ---- degree count: one thread per edge, +1.0 into cnt[dst] ----
__global__ void k_count(const int* __restrict__ dst, float* __restrict__ cnt, int n) {
    int e = blockIdx.x * 256 + threadIdx.x;
    if (e < n) unsafeAtomicAdd(&cnt[dst[e]], 1.0f);
}

// ---- cnt -> 1/max(cnt,1) ----
__global__ void k_inv(float* __restrict__ c, int n) {
    int i = blockIdx.x * 256 + threadIdx.x;
    if (i < n) c[i] = 1.0f / fmaxf(c[i], 1.0f);
}

// ---- y[n,32] = x[n,F] @ w[F,32]; one thread per row, weights via scalar loads ----
template<int F>
__global__ void k_linear(const float* __restrict__ x, const float* __restrict__ w,
                         float* __restrict__ y, int n) {
    int i = blockIdx.x * 256 + threadIdx.x;
    if (i >= n) return;
    const float* xr = x + (size_t)i * F;
    float acc[HID];
#pragma unroll
    for (int j = 0; j < HID; ++j) acc[j] = 0.0f;
#pragma unroll
    for (int k = 0; k < F; ++k) {
        float xk = xr[k];
#pragma unroll
        for (int j = 0; j < HID; ++j) acc[j] = __builtin_fmaf(xk, w[k * HID + j], acc[j]);
    }
    float* yr = y + (size_t)i * HID;
#pragma unroll
    for (int j = 0; j < HID; ++j) yr[j] = acc[j];
}

// ---- scatter: 32 threads per edge, acc[dst][j] += pre[src][j] ----
__global__ void k_scatter(const int* __restrict__ ei, const float* __restrict__ pre,
                          float* __restrict__ acc, int ne) {
    long gid = (long)blockIdx.x * 256 + threadIdx.x;
    int e = (int)(gid >> 5);
    if (e >= ne) return;
    int j = (int)(gid & 31);
    int s = ei[e];
    int d = ei[ne + e];
    unsafeAtomicAdd(&acc[(size_t)d * HID + j], pre[(size_t)s * HID + j]);
}

// ---- finalize in-place: acc = relu(acc*inv + x_dst@w + b) ----
template<int F>
__global__ void k_finalize(float* __restrict__ acc, const float* __restrict__ xd,
                           const float* __restrict__ w, const float* __restrict__ b,
                           const float* __restrict__ inv, int n) {
    int i = blockIdx.x * 256 + threadIdx.x;
    if (i >= n) return;
    float s[HID];
#pragma unroll
    for (int j = 0; j < HID; ++j) s[j] = b[j];
    const float* xr = xd + (size_t)i * F;
#pragma unroll
    for (int k = 0; k < F; ++k) {
        float xk = xr[k];
#pragma unroll
        for (int j = 0; j < HID; ++j) s[j] = __builtin_fmaf(xk, w[k * HID + j], s[j]);
    }
    float iv = inv[i];
    float* ar = acc + (size_t)i * HID;
#pragma unroll
    for (int j = 0; j < HID; ++j) {
        float v = __builtin_fmaf(ar[j], iv, s[j]);
        ar[j] = v > 0.0f ? v : 0.0f;
    }
}

// ---- classifier: out[n,2] = h[n,32] @ w[32,2] + b ----
__global__ void k_out(const float* __restrict__ h, const float* __restrict__ w,
                      const float* __restrict__ b, float* __restrict__ out, int n) {
    int i = blockIdx.x * 256 + threadIdx.x;
    if (i >= n) return;
    float a0 = b[0], a1 = b[1];
    const float* hr = h + (size_t)i * HID;
#pragma unroll
    for (int k = 0; k < HID; ++k) {
        float hk = hr[k];
        a0 = __builtin_fmaf(hk, w[k * 2 + 0], a0);
        a1 = __builtin_fmaf(hk, w[k * 2 + 1], a1);
    }
    out[(size_t)i * 2 + 0] = a0;
    out[(size_t)i * 2 + 1] = a1;
}

extern "C" void kernel_launch(void* const* d_in, const int* in_sizes, int n_in,
                              void* d_out, int out_size, void* d_ws, size_t ws_size,
                              hipStream_t stream) {
    const float* x_addr  = (const float*)d_in[0];
    const float* x_tx    = (const float*)d_in[1];
    const int*   ei_at   = (const int*)d_in[2];
    const int*   ei_ta   = (const int*)d_in[3];
    const float* w1_tx_l = (const float*)d_in[4];  const float* b1_tx = (const float*)d_in[5];
    const float* w1_tx_r = (const float*)d_in[6];
    const float* w1_ad_l = (const float*)d_in[7];  const float* b1_ad = (const float*)d_in[8];
    const float* w1_ad_r = (const float*)d_in[9];
    const float* w2_tx_l = (const float*)d_in[10]; const float* b2_tx = (const float*)d_in[11];
    const float* w2_tx_r = (const float*)d_in[12];
    const float* w2_ad_l = (const float*)d_in[13]; const float* b2_ad = (const float*)d_in[14];
    const float* w2_ad_r = (const float*)d_in[15];
    // d_in[16..18] = w3_tx_l, b3_tx, w3_tx_r -- unused by the reference
    const float* w3_ad_l = (const float*)d_in[19]; const float* b3_ad = (const float*)d_in[20];
    const float* w3_ad_r = (const float*)d_in[21];
    const float* w_out   = (const float*)d_in[22]; const float* b_out = (const float*)d_in[23];
    float* out = (float*)d_out;

    float* ws = (float*)d_ws;
    float* inv_tx = ws;              // NTX counts -> inv
    float* inv_ad = ws + NTX;        // NADDR counts -> inv
    const size_t SLOT = (size_t)400000 * HID;   // 12.8M floats per slot
    float* S0 = ws + NTX + NADDR;    // pre buffer
    float* S1 = S0 + SLOT;
    float* S2 = S1 + SLOT;
    float* S3 = S2 + SLOT;
    float* S4 = S3 + SLOT;

    dim3 blk(256);
    int gN = cdiv_host(400000, 256);
    int gE = cdiv_host(NEDGE, 256);
    int gS = cdiv_host((long)NEDGE * 32, 256);

    // ---- degrees (recomputed every call; deterministic) ----
    hipMemsetAsync(inv_tx, 0, (size_t)(NTX + NADDR) * sizeof(float), stream);
    k_count<<<gE, blk, 0, stream>>>(ei_at + NEDGE, inv_tx, NEDGE);
    k_count<<<gE, blk, 0, stream>>>(ei_ta + NEDGE, inv_ad, NEDGE);
    k_inv<<<cdiv_host(NTX + NADDR, 256), blk, 0, stream>>>(inv_tx, NTX + NADDR);

    // ---- layer 1: tx = relu(mean_{at}(x_addr@w1_tx_l) + x_tx@w1_tx_r + b1_tx) ----
    k_linear<FIN><<<gN, blk, 0, stream>>>(x_addr, w1_tx_l, S0, NADDR);
    hipMemsetAsync(S1, 0, SLOT * sizeof(float), stream);
    k_scatter<<<gS, blk, 0, stream>>>(ei_at, S0, S1, NEDGE);
    k_finalize<FIN><<<gN, blk, 0, stream>>>(S1, x_tx, w1_tx_r, b1_tx, inv_tx, NTX);

    // ---- layer 1: ad ----
    k_linear<FIN><<<gN, blk, 0, stream>>>(x_tx, w1_ad_l, S0, NTX);
    hipMemsetAsync(S2, 0, SLOT * sizeof(float), stream);
    k_scatter<<<gS, blk, 0, stream>>>(ei_ta, S0, S2, NEDGE);
    k_finalize<FIN><<<gN, blk, 0, stream>>>(S2, x_addr, w1_ad_r, b1_ad, inv_ad, NADDR);

    // ---- layer 2: tx2 (src = ad in S2, self = tx in S1) -> S3 ----
    k_linear<HID><<<gN, blk, 0, stream>>>(S2, w2_tx_l, S0, NADDR);
    hipMemsetAsync(S3, 0, SLOT * sizeof(float), stream);
    k_scatter<<<gS, blk, 0, stream>>>(ei_at, S0, S3, NEDGE);
    k_finalize<HID><<<gN, blk, 0, stream>>>(S3, S1, w2_tx_r, b2_tx, inv_tx, NTX);

    // ---- layer 2: ad2 (src = tx in S1, self = ad in S2) -> S4 ----
    k_linear<HID><<<gN, blk, 0, stream>>>(S1, w2_ad_l, S0, NTX);
    hipMemsetAsync(S4, 0, SLOT * sizeof(float), stream);
    k_scatter<<<gS, blk, 0, stream>>>(ei_ta, S0, S4, NEDGE);
    k_finalize<HID><<<gN, blk, 0, stream>>>(S4, S2, w2_ad_r, b2_ad, inv_ad, NADDR);

    // ---- layer 3: ad3 (src = tx2 in S3, self = ad2 in S4) -> S1 (reuse) ----
    k_linear<HID><<<gN, blk, 0, stream>>>(S3, w3_ad_l, S0, NTX);
    hipMemsetAsync(S1, 0, SLOT * sizeof(float), stream);
    k_scatter<<<gS, blk, 0, stream>>>(ei_ta, S0, S1, NEDGE);
    k_finalize<HID><<<gN, blk, 0, stream>>>(S1, S4, w3_ad_r, b3_ad, inv_ad, NADDR);

    // ---- classifier ----
    k_out<<<gN, blk, 0, stream>>>(S1, w_out, b_out, out, NADDR);
}

// Round 2
// 1397.065 us; speedup vs baseline: 1.0691x; 1.0691x over previous
//
#include <hip/hip_runtime.h>

#define NADDR 400000
#define NTX   400000
#define NEDGE 1500000
#define FIN   64
#define HID   32

static inline int cdiv_host(long a, int b) { return (int)((a + b - 1) / b); }

// ---- int degree count: one thread per edge ----
__global__ void k_counti(const int* __restrict__ dst, int* __restrict__ cnt, int ne) {
    int e = blockIdx.x * 256 + threadIdx.x;
    if (e < ne) atomicAdd(&cnt[dst[e]], 1);
}

// ---- per-block exclusive scan; block totals to bsum ----
__global__ void k_scan_block(const int* __restrict__ cnt, int* __restrict__ excl,
                             int* __restrict__ bsum, int n) {
    __shared__ int sm[256];
    int t = threadIdx.x;
    int i = blockIdx.x * 256 + t;
    int v = (i < n) ? cnt[i] : 0;
    sm[t] = v;
    __syncthreads();
    for (int off = 1; off < 256; off <<= 1) {
        int x = (t >= off) ? sm[t - off] : 0;
        __syncthreads();
        sm[t] += x;
        __syncthreads();
    }
    if (i < n) excl[i] = sm[t] - v;
    if (t == 255) bsum[blockIdx.x] = sm[255];
}

// ---- single-block scan of block totals (sequential 256-chunks) ----
__global__ void k_scan_tops(int* __restrict__ bsum, int nb) {
    __shared__ int sm[256];
    __shared__ int carry;
    int t = threadIdx.x;
    if (t == 0) carry = 0;
    __syncthreads();
    for (int base = 0; base < nb; base += 256) {
        int i = base + t;
        int v = (i < nb) ? bsum[i] : 0;
        sm[t] = v;
        __syncthreads();
        for (int off = 1; off < 256; off <<= 1) {
            int x = (t >= off) ? sm[t - off] : 0;
            __syncthreads();
            sm[t] += x;
            __syncthreads();
        }
        int incl = sm[t];
        int tot  = sm[255];
        int c    = carry;
        if (i < nb) bsum[i] = incl - v + c;
        __syncthreads();
        if (t == 0) carry = c + tot;
        __syncthreads();
    }
}

// ---- add block offsets; write row_ptr[n] ----
__global__ void k_scan_add(int* __restrict__ rp, const int* __restrict__ bsum,
                           int n, int total) {
    int i = blockIdx.x * 256 + threadIdx.x;
    if (i < n) rp[i] += bsum[blockIdx.x];
    if (i == 0) rp[n] = total;
}

__global__ void k_copy(const int* __restrict__ a, int* __restrict__ b, int n) {
    int i = blockIdx.x * 256 + threadIdx.x;
    if (i < n) b[i] = a[i];
}

// ---- CSR fill: col[cursor[dst]++] = src ----
__global__ void k_fill(const int* __restrict__ ei, int* __restrict__ cursor,
                       int* __restrict__ col, int ne) {
    int e = blockIdx.x * 256 + threadIdx.x;
    if (e >= ne) return;
    int s = ei[e];
    int d = ei[ne + e];
    int idx = atomicAdd(&cursor[d], 1);
    col[idx] = s;
}

// ---- y[n,32] = x[n,F] @ w[F,32]; one thread per row ----
template<int F>
__global__ void k_linear(const float* __restrict__ x, const float* __restrict__ w,
                         float* __restrict__ y, int n) {
    int i = blockIdx.x * 256 + threadIdx.x;
    if (i >= n) return;
    const float* xr = x + (size_t)i * F;
    float acc[HID];
#pragma unroll
    for (int j = 0; j < HID; ++j) acc[j] = 0.0f;
#pragma unroll
    for (int k = 0; k < F; ++k) {
        float xk = xr[k];
#pragma unroll
        for (int j = 0; j < HID; ++j) acc[j] = __builtin_fmaf(xk, w[k * HID + j], acc[j]);
    }
    float* yr = y + (size_t)i * HID;
#pragma unroll
    for (int j = 0; j < HID; ++j) yr[j] = acc[j];
}

// ---- fused aggregate + finalize (+ optional classifier) ----
// 32 lanes per dst node: gather-sum pre over CSR neighbors, scale by 1/deg,
// add x_dst@w + b, relu. xd/y may alias (in-place row update is wave-safe).
template<int F, bool FINAL>
__global__ void k_agg(const int* __restrict__ rp, const int* __restrict__ col,
                      const float* __restrict__ pre,
                      const float* xd,              // self features [n,F]
                      const float* __restrict__ w,  // [F,32]
                      const float* __restrict__ b,  // [32]
                      float* y,                     // [n,32] or final [n,2]
                      const float* __restrict__ wo, // [32,2] (FINAL)
                      const float* __restrict__ bo, // [2]    (FINAL)
                      int n) {
    int t = blockIdx.x * 256 + threadIdx.x;
    int g = t >> 5;      // node
    int j = t & 31;      // feature
    if (g >= n) return;
    int p0 = rp[g], p1 = rp[g + 1];
    float acc = 0.0f;
    for (int k = p0; k < p1; ++k) {
        int s = col[k];  // uniform within the 32-lane group
        acc += pre[(size_t)s * HID + j];
    }
    float inv = 1.0f / fmaxf((float)(p1 - p0), 1.0f);

    float h = b[j];
    const float* xr = xd + (size_t)g * F;
    float xv0 = xr[j];
    float xv1 = (F == 64) ? xr[32 + j] : 0.0f;
#pragma unroll
    for (int k = 0; k < 32; ++k) {
        float xk = __shfl(xv0, k, 32);
        h = __builtin_fmaf(xk, w[k * HID + j], h);
        if (F == 64) {
            float xk1 = __shfl(xv1, k, 32);
            h = __builtin_fmaf(xk1, w[(k + 32) * HID + j], h);
        }
    }
    float v = __builtin_fmaf(acc, inv, h);
    v = v > 0.0f ? v : 0.0f;

    if (!FINAL) {
        y[(size_t)g * HID + j] = v;
    } else {
        float o0 = v * wo[j * 2 + 0];
        float o1 = v * wo[j * 2 + 1];
#pragma unroll
        for (int m = 16; m >= 1; m >>= 1) {
            o0 += __shfl_xor(o0, m, 32);
            o1 += __shfl_xor(o1, m, 32);
        }
        if (j == 0) {
            y[(size_t)g * 2 + 0] = o0 + bo[0];
            y[(size_t)g * 2 + 1] = o1 + bo[1];
        }
    }
}

extern "C" void kernel_launch(void* const* d_in, const int* in_sizes, int n_in,
                              void* d_out, int out_size, void* d_ws, size_t ws_size,
                              hipStream_t stream) {
    const float* x_addr  = (const float*)d_in[0];
    const float* x_tx    = (const float*)d_in[1];
    const int*   ei_at   = (const int*)d_in[2];
    const int*   ei_ta   = (const int*)d_in[3];
    const float* w1_tx_l = (const float*)d_in[4];  const float* b1_tx = (const float*)d_in[5];
    const float* w1_tx_r = (const float*)d_in[6];
    const float* w1_ad_l = (const float*)d_in[7];  const float* b1_ad = (const float*)d_in[8];
    const float* w1_ad_r = (const float*)d_in[9];
    const float* w2_tx_l = (const float*)d_in[10]; const float* b2_tx = (const float*)d_in[11];
    const float* w2_tx_r = (const float*)d_in[12];
    const float* w2_ad_l = (const float*)d_in[13]; const float* b2_ad = (const float*)d_in[14];
    const float* w2_ad_r = (const float*)d_in[15];
    // d_in[16..18] unused (w3_tx_*)
    const float* w3_ad_l = (const float*)d_in[19]; const float* b3_ad = (const float*)d_in[20];
    const float* w3_ad_r = (const float*)d_in[21];
    const float* w_out   = (const float*)d_in[22]; const float* b_out = (const float*)d_in[23];
    float* out = (float*)d_out;

    // ---- workspace carve ----
    char* base = (char*)d_ws;
    int* rp_tx  = (int*)base;                 base += (size_t)(NTX + 1) * 4;
    int* rp_ad  = (int*)base;                 base += (size_t)(NADDR + 1) * 4;
    int* col_at = (int*)base;                 base += (size_t)NEDGE * 4;
    int* col_ta = (int*)base;                 base += (size_t)NEDGE * 4;
    int* cursor = (int*)base;                 base += (size_t)400000 * 4;
    int* bsum   = (int*)base;                 base += (size_t)2048 * 4;
    base = (char*)(((size_t)base + 255) & ~(size_t)255);
    const size_t SLOT = (size_t)400000 * HID;
    float* S0 = (float*)base;                 // pre scratch
    float* S1 = S0 + SLOT;                    // tx
    float* S2 = S1 + SLOT;                    // ad -> ad2 (in place)
    float* S3 = S2 + SLOT;                    // tx2

    dim3 blk(256);
    int gN  = cdiv_host(400000, 256);         // 1563 (also #scan blocks)
    int gE  = cdiv_host(NEDGE, 256);
    int gG  = cdiv_host((long)400000 * 32, 256);

    // ---- build CSR for at (dst = tx) ----
    hipMemsetAsync(cursor, 0, (size_t)NTX * 4, stream);
    k_counti<<<gE, blk, 0, stream>>>(ei_at + NEDGE, cursor, NEDGE);
    k_scan_block<<<gN, blk, 0, stream>>>(cursor, rp_tx, bsum, NTX);
    k_scan_tops<<<1, blk, 0, stream>>>(bsum, gN);
    k_scan_add<<<gN, blk, 0, stream>>>(rp_tx, bsum, NTX, NEDGE);
    k_copy<<<gN, blk, 0, stream>>>(rp_tx, cursor, NTX);
    k_fill<<<gE, blk, 0, stream>>>(ei_at, cursor, col_at, NEDGE);

    // ---- build CSR for ta (dst = ad) ----
    hipMemsetAsync(cursor, 0, (size_t)NADDR * 4, stream);
    k_counti<<<gE, blk, 0, stream>>>(ei_ta + NEDGE, cursor, NEDGE);
    k_scan_block<<<gN, blk, 0, stream>>>(cursor, rp_ad, bsum, NADDR);
    k_scan_tops<<<1, blk, 0, stream>>>(bsum, gN);
    k_scan_add<<<gN, blk, 0, stream>>>(rp_ad, bsum, NADDR, NEDGE);
    k_copy<<<gN, blk, 0, stream>>>(rp_ad, cursor, NADDR);
    k_fill<<<gE, blk, 0, stream>>>(ei_ta, cursor, col_ta, NEDGE);

    // ---- layer 1: tx = relu(mean_at(x_addr@w1_tx_l) + x_tx@w1_tx_r + b1_tx) ----
    k_linear<FIN><<<gN, blk, 0, stream>>>(x_addr, w1_tx_l, S0, NADDR);
    k_agg<FIN, false><<<gG, blk, 0, stream>>>(rp_tx, col_at, S0, x_tx, w1_tx_r, b1_tx,
                                              S1, nullptr, nullptr, NTX);
    // ---- layer 1: ad ----
    k_linear<FIN><<<gN, blk, 0, stream>>>(x_tx, w1_ad_l, S0, NTX);
    k_agg<FIN, false><<<gG, blk, 0, stream>>>(rp_ad, col_ta, S0, x_addr, w1_ad_r, b1_ad,
                                              S2, nullptr, nullptr, NADDR);
    // ---- layer 2: tx2 (src = ad(S2), self = tx(S1)) -> S3 ----
    k_linear<HID><<<gN, blk, 0, stream>>>(S2, w2_tx_l, S0, NADDR);
    k_agg<HID, false><<<gG, blk, 0, stream>>>(rp_tx, col_at, S0, S1, w2_tx_r, b2_tx,
                                              S3, nullptr, nullptr, NTX);
    // ---- layer 2: ad2 (src = tx(S1), self = ad(S2)) -> S2 in place ----
    k_linear<HID><<<gN, blk, 0, stream>>>(S1, w2_ad_l, S0, NTX);
    k_agg<HID, false><<<gG, blk, 0, stream>>>(rp_ad, col_ta, S0, S2, w2_ad_r, b2_ad,
                                              S2, nullptr, nullptr, NADDR);
    // ---- layer 3 + classifier: ad3 (src = tx2(S3), self = ad2(S2)) -> out ----
    k_linear<HID><<<gN, blk, 0, stream>>>(S3, w3_ad_l, S0, NTX);
    k_agg<HID, true><<<gG, blk, 0, stream>>>(rp_ad, col_ta, S0, S2, w3_ad_r, b3_ad,
                                             out, w_out, b_out, NADDR);
}

// Round 3
// 1197.013 us; speedup vs baseline: 1.2478x; 1.1671x over previous
//
#include <hip/hip_runtime.h>

#define NADDR 400000
#define NTX   400000
#define NEDGE 1500000
#define FIN   64
#define HID   32

static inline int cdiv_host(long a, int b) { return (int)((a + b - 1) / b); }

// ================= CSR build (both edge types fused per launch) =============

// count in-degree: blocks [0,gE) handle at (dst=tx -> cnt[0..NTX)),
// blocks [gE,2gE) handle ta (dst=ad -> cnt[NTX..NTX+NADDR))
__global__ void k_count2(const int* __restrict__ at_dst, const int* __restrict__ ta_dst,
                         int* __restrict__ cnt, int gE) {
    bool wh = blockIdx.x >= gE;
    int e = (blockIdx.x - (wh ? gE : 0)) * 256 + threadIdx.x;
    if (e >= NEDGE) return;
    if (!wh) atomicAdd(&cnt[at_dst[e]], 1);
    else     atomicAdd(&cnt[NTX + ta_dst[e]], 1);
}

// per-block exclusive scan into rp_tx / rp_ad; block totals into bsum[blockIdx]
__global__ void k_scan_block2(const int* __restrict__ cnt, int* __restrict__ rp_tx,
                              int* __restrict__ rp_ad, int* __restrict__ bsum, int gN) {
    __shared__ int sm[256];
    bool wh = blockIdx.x >= gN;
    int bb = blockIdx.x - (wh ? gN : 0);
    int t = threadIdx.x;
    int i = bb * 256 + t;
    int v = (i < 400000) ? cnt[(wh ? NTX : 0) + i] : 0;
    sm[t] = v;
    __syncthreads();
    for (int off = 1; off < 256; off <<= 1) {
        int x = (t >= off) ? sm[t - off] : 0;
        __syncthreads();
        sm[t] += x;
        __syncthreads();
    }
    int* rp = wh ? rp_ad : rp_tx;
    if (i < 400000) rp[i] = sm[t] - v;
    if (t == 255) bsum[blockIdx.x] = sm[255];
}

// 2 blocks; block b scans bsum[b*nb .. b*nb+nb) exclusively (serial 256-chunks)
__global__ void k_scan_tops2(int* __restrict__ bsum, int nb) {
    __shared__ int sm[256];
    __shared__ int carry;
    int t = threadIdx.x;
    int off0 = blockIdx.x * nb;
    if (t == 0) carry = 0;
    __syncthreads();
    for (int base = 0; base < nb; base += 256) {
        int i = base + t;
        int v = (i < nb) ? bsum[off0 + i] : 0;
        sm[t] = v;
        __syncthreads();
        for (int off = 1; off < 256; off <<= 1) {
            int x = (t >= off) ? sm[t - off] : 0;
            __syncthreads();
            sm[t] += x;
            __syncthreads();
        }
        int incl = sm[t], tot = sm[255], c = carry;
        if (i < nb) bsum[off0 + i] = incl - v + c;
        __syncthreads();
        if (t == 0) carry = c + tot;
        __syncthreads();
    }
}

// add block offsets; also write cursor copy and rp[400000]=NEDGE
__global__ void k_scan_add2(int* __restrict__ rp_tx, int* __restrict__ rp_ad,
                            int* __restrict__ cursor, const int* __restrict__ bsum, int gN) {
    bool wh = blockIdx.x >= gN;
    int bb = blockIdx.x - (wh ? gN : 0);
    int i = bb * 256 + threadIdx.x;
    int* rp = wh ? rp_ad : rp_tx;
    if (i < 400000) {
        int v = rp[i] + bsum[blockIdx.x];
        rp[i] = v;
        cursor[(wh ? NTX : 0) + i] = v;
    }
    if (i == 0) rp[400000] = NEDGE;
}

__global__ void k_fill2(const int* __restrict__ ei_at, const int* __restrict__ ei_ta,
                        int* __restrict__ cursor, int* __restrict__ col_at,
                        int* __restrict__ col_ta, int gE) {
    bool wh = blockIdx.x >= gE;
    int e = (blockIdx.x - (wh ? gE : 0)) * 256 + threadIdx.x;
    if (e >= NEDGE) return;
    const int* ei = wh ? ei_ta : ei_at;
    int s = ei[e];
    int d = ei[NEDGE + e];
    int idx = atomicAdd(&cursor[(wh ? NTX : 0) + d], 1);
    (wh ? col_ta : col_at)[idx] = s;
}

// ================= dense pre-transform (layer 1 only) =======================

template<int F>
__global__ void k_linear(const float* __restrict__ x, const float* __restrict__ w,
                         float* __restrict__ y, int n) {
    int i = blockIdx.x * 256 + threadIdx.x;
    if (i >= n) return;
    const float4* xr = (const float4*)(x + (size_t)i * F);
    float acc[HID];
#pragma unroll
    for (int j = 0; j < HID; ++j) acc[j] = 0.0f;
#pragma unroll
    for (int k4 = 0; k4 < F / 4; ++k4) {
        float4 xv = xr[k4];
        const float* wr = w + k4 * 4 * HID;
#pragma unroll
        for (int j = 0; j < HID; ++j) acc[j] = __builtin_fmaf(xv.x, wr[j], acc[j]);
#pragma unroll
        for (int j = 0; j < HID; ++j) acc[j] = __builtin_fmaf(xv.y, wr[HID + j], acc[j]);
#pragma unroll
        for (int j = 0; j < HID; ++j) acc[j] = __builtin_fmaf(xv.z, wr[2 * HID + j], acc[j]);
#pragma unroll
        for (int j = 0; j < HID; ++j) acc[j] = __builtin_fmaf(xv.w, wr[3 * HID + j], acc[j]);
    }
    float* yr = y + (size_t)i * HID;
#pragma unroll
    for (int j = 0; j < HID; j += 4) {
        float4 o = make_float4(acc[j], acc[j + 1], acc[j + 2], acc[j + 3]);
        *(float4*)(yr + j) = o;
    }
}

// ================= fused SAGE aggregation ===================================
// 32 lanes per dst node. Gather-sum src rows (8-way batched for MLP), mean,
// optional Wl via shfl broadcast (PRE=false), self-term xd@Wr via shfl, +b,
// relu, then either store [n,32] or apply the final 32->2 classifier.
template<int F, bool PRE, bool FINAL>
__global__ void k_agg(const int* __restrict__ rp, const int* __restrict__ col,
                      const float* __restrict__ src,   // [*,32] pre (PRE) or raw feats
                      const float* xd,                 // [n,F] self feats (may alias y)
                      const float* __restrict__ wl,    // [32,32] (only !PRE)
                      const float* __restrict__ w,     // [F,32]
                      const float* __restrict__ b,     // [32]
                      float* y,                        // [n,32] or [n,2] (FINAL)
                      const float* __restrict__ wo,    // [32,2] (FINAL)
                      const float* __restrict__ bo,    // [2]    (FINAL)
                      int n) {
    int t = blockIdx.x * 256 + threadIdx.x;
    int g = t >> 5;
    int j = t & 31;
    if (g >= n) return;
    int p0 = rp[g], p1 = rp[g + 1];

    float acc = 0.0f;
    for (int k = p0; k < p1; k += 8) {
        int last = p1 - 1;
        int c1 = k + 1 < p1 ? k + 1 : last;
        int c2 = k + 2 < p1 ? k + 2 : last;
        int c3 = k + 3 < p1 ? k + 3 : last;
        int c4 = k + 4 < p1 ? k + 4 : last;
        int c5 = k + 5 < p1 ? k + 5 : last;
        int c6 = k + 6 < p1 ? k + 6 : last;
        int c7 = k + 7 < p1 ? k + 7 : last;
        int s0 = col[k],  s1 = col[c1], s2 = col[c2], s3 = col[c3];
        int s4 = col[c4], s5 = col[c5], s6 = col[c6], s7 = col[c7];
        float v0 = src[(size_t)s0 * HID + j];
        float v1 = src[(size_t)s1 * HID + j];
        float v2 = src[(size_t)s2 * HID + j];
        float v3 = src[(size_t)s3 * HID + j];
        float v4 = src[(size_t)s4 * HID + j];
        float v5 = src[(size_t)s5 * HID + j];
        float v6 = src[(size_t)s6 * HID + j];
        float v7 = src[(size_t)s7 * HID + j];
        acc += v0;
        acc += (k + 1 < p1) ? v1 : 0.0f;
        acc += (k + 2 < p1) ? v2 : 0.0f;
        acc += (k + 3 < p1) ? v3 : 0.0f;
        acc += (k + 4 < p1) ? v4 : 0.0f;
        acc += (k + 5 < p1) ? v5 : 0.0f;
        acc += (k + 6 < p1) ? v6 : 0.0f;
        acc += (k + 7 < p1) ? v7 : 0.0f;
    }
    float inv = 1.0f / fmaxf((float)(p1 - p0), 1.0f);
    float am = acc * inv;

    float h = b[j];
    if (PRE) {
        h += am;
    } else {
#pragma unroll
        for (int k = 0; k < 32; ++k)
            h = __builtin_fmaf(__shfl(am, k, 32), wl[k * HID + j], h);
    }

    const float* xr = xd + (size_t)g * F;
    float xv0 = xr[j];
    float xv1 = (F == 64) ? xr[32 + j] : 0.0f;
#pragma unroll
    for (int k = 0; k < 32; ++k) {
        h = __builtin_fmaf(__shfl(xv0, k, 32), w[k * HID + j], h);
        if (F == 64)
            h = __builtin_fmaf(__shfl(xv1, k, 32), w[(k + 32) * HID + j], h);
    }
    float v = h > 0.0f ? h : 0.0f;

    if (!FINAL) {
        y[(size_t)g * HID + j] = v;
    } else {
        float o0 = v * wo[j * 2 + 0];
        float o1 = v * wo[j * 2 + 1];
#pragma unroll
        for (int m = 16; m >= 1; m >>= 1) {
            o0 += __shfl_xor(o0, m, 32);
            o1 += __shfl_xor(o1, m, 32);
        }
        if (j == 0) {
            y[(size_t)g * 2 + 0] = o0 + bo[0];
            y[(size_t)g * 2 + 1] = o1 + bo[1];
        }
    }
}

// ============================================================================

extern "C" void kernel_launch(void* const* d_in, const int* in_sizes, int n_in,
                              void* d_out, int out_size, void* d_ws, size_t ws_size,
                              hipStream_t stream) {
    const float* x_addr  = (const float*)d_in[0];
    const float* x_tx    = (const float*)d_in[1];
    const int*   ei_at   = (const int*)d_in[2];
    const int*   ei_ta   = (const int*)d_in[3];
    const float* w1_tx_l = (const float*)d_in[4];  const float* b1_tx = (const float*)d_in[5];
    const float* w1_tx_r = (const float*)d_in[6];
    const float* w1_ad_l = (const float*)d_in[7];  const float* b1_ad = (const float*)d_in[8];
    const float* w1_ad_r = (const float*)d_in[9];
    const float* w2_tx_l = (const float*)d_in[10]; const float* b2_tx = (const float*)d_in[11];
    const float* w2_tx_r = (const float*)d_in[12];
    const float* w2_ad_l = (const float*)d_in[13]; const float* b2_ad = (const float*)d_in[14];
    const float* w2_ad_r = (const float*)d_in[15];
    // d_in[16..18] unused (w3_tx_*)
    const float* w3_ad_l = (const float*)d_in[19]; const float* b3_ad = (const float*)d_in[20];
    const float* w3_ad_r = (const float*)d_in[21];
    const float* w_out   = (const float*)d_in[22]; const float* b_out = (const float*)d_in[23];
    float* out = (float*)d_out;

    // ---- workspace carve ----
    char* base = (char*)d_ws;
    int* cnt    = (int*)base;  base += (size_t)(NTX + NADDR) * 4;   // doubles as cursor
    int* rp_tx  = (int*)base;  base += (size_t)(NTX + 1) * 4;
    int* rp_ad  = (int*)base;  base += (size_t)(NADDR + 1) * 4;
    int* col_at = (int*)base;  base += (size_t)NEDGE * 4;
    int* col_ta = (int*)base;  base += (size_t)NEDGE * 4;
    int* bsum   = (int*)base;  base += (size_t)4096 * 4;
    base = (char*)(((size_t)base + 255) & ~(size_t)255);
    const size_t SLOT = (size_t)400000 * HID;
    float* S0 = (float*)base;   // pre scratch (layer 1)
    float* S1 = S0 + SLOT;      // tx
    float* S2 = S1 + SLOT;      // ad -> ad2 (in place)
    float* S3 = S2 + SLOT;      // tx2

    dim3 blk(256);
    int gN = cdiv_host(400000, 256);              // 1563
    int gE = cdiv_host(NEDGE, 256);               // 5860
    int gG = cdiv_host((long)400000 * 32, 256);   // 50000

    // ---- CSR build (both edge types) ----
    hipMemsetAsync(cnt, 0, (size_t)(NTX + NADDR) * 4, stream);
    k_count2<<<2 * gE, blk, 0, stream>>>(ei_at + NEDGE, ei_ta + NEDGE, cnt, gE);
    k_scan_block2<<<2 * gN, blk, 0, stream>>>(cnt, rp_tx, rp_ad, bsum, gN);
    k_scan_tops2<<<2, blk, 0, stream>>>(bsum, gN);
    k_scan_add2<<<2 * gN, blk, 0, stream>>>(rp_tx, rp_ad, cnt, bsum, gN);
    k_fill2<<<2 * gE, blk, 0, stream>>>(ei_at, ei_ta, cnt, col_at, col_ta, gE);

    // ---- layer 1: tx = relu(mean_at(x_addr@w1_tx_l) + x_tx@w1_tx_r + b1_tx) ----
    k_linear<FIN><<<gN, blk, 0, stream>>>(x_addr, w1_tx_l, S0, NADDR);
    k_agg<FIN, true, false><<<gG, blk, 0, stream>>>(rp_tx, col_at, S0, x_tx, nullptr,
                                                    w1_tx_r, b1_tx, S1, nullptr, nullptr, NTX);
    // ---- layer 1: ad ----
    k_linear<FIN><<<gN, blk, 0, stream>>>(x_tx, w1_ad_l, S0, NTX);
    k_agg<FIN, true, false><<<gG, blk, 0, stream>>>(rp_ad, col_ta, S0, x_addr, nullptr,
                                                    w1_ad_r, b1_ad, S2, nullptr, nullptr, NADDR);
    // ---- layer 2: tx2 = relu(mean_at(ad)@w2_tx_l + tx@w2_tx_r + b2_tx) -> S3 ----
    k_agg<HID, false, false><<<gG, blk, 0, stream>>>(rp_tx, col_at, S2, S1, w2_tx_l,
                                                     w2_tx_r, b2_tx, S3, nullptr, nullptr, NTX);
    // ---- layer 2: ad2 = relu(mean_ta(tx)@w2_ad_l + ad@w2_ad_r + b2_ad) -> S2 in place ----
    k_agg<HID, false, false><<<gG, blk, 0, stream>>>(rp_ad, col_ta, S1, S2, w2_ad_l,
                                                     w2_ad_r, b2_ad, S2, nullptr, nullptr, NADDR);
    // ---- layer 3 + classifier: ad3 -> out ----
    k_agg<HID, false, true><<<gG, blk, 0, stream>>>(rp_ad, col_ta, S3, S2, w3_ad_l,
                                                    w3_ad_r, b3_ad, out, w_out, b_out, NADDR);
}

// Round 4
// 976.203 us; speedup vs baseline: 1.5300x; 1.2262x over previous
//
#include <hip/hip_runtime.h>

#define NADDR 400000
#define NTX   400000
#define NEDGE 1500000
#define FIN   64
#define HID   32
#define NB    1563        // buckets per node type; 256 nodes per bucket

static inline int cdiv_host(long a, int b) { return (int)((a + b - 1) / b); }

// ================= bucketed CSR build =======================================
// Bucket b covers dst nodes [b*256, b*256+256). Edges land in their bucket's
// contiguous region of eb_*; then one block per bucket emits exact CSR with
// all scattered accesses confined to LDS / a tiny L2-resident col window.

// ---- per-bucket histogram (LDS-aggregated), both edge types ----
__global__ void k_hist(const int* __restrict__ at_dst, const int* __restrict__ ta_dst,
                       int* __restrict__ bcnt /*[2*NB]*/, int GH) {
    __shared__ int h[NB];
    bool wh = blockIdx.x >= GH;
    int blk = blockIdx.x - (wh ? GH : 0);
    const int* dst = wh ? ta_dst : at_dst;
    for (int i = threadIdx.x; i < NB; i += 256) h[i] = 0;
    __syncthreads();
    for (long e = (long)blk * 256 + threadIdx.x; e < NEDGE; e += (long)GH * 256)
        atomicAdd(&h[dst[e] >> 8], 1);
    __syncthreads();
    int* g = bcnt + (wh ? NB : 0);
    for (int i = threadIdx.x; i < NB; i += 256) {
        int v = h[i];
        if (v) atomicAdd(&g[i], v);
    }
}

// ---- 2 blocks: exclusive scan of each type's NB bucket counts ----
__global__ void k_scan_nb(const int* __restrict__ bcnt, int* __restrict__ bbase,
                          int* __restrict__ gcur) {
    __shared__ int sm[256];
    __shared__ int carry;
    int w = blockIdx.x;
    int t = threadIdx.x;
    if (t == 0) carry = 0;
    __syncthreads();
    for (int base = 0; base < NB; base += 256) {
        int i = base + t;
        int v = (i < NB) ? bcnt[w * NB + i] : 0;
        sm[t] = v;
        __syncthreads();
        for (int off = 1; off < 256; off <<= 1) {
            int x = (t >= off) ? sm[t - off] : 0;
            __syncthreads();
            sm[t] += x;
            __syncthreads();
        }
        int excl = sm[t] - v + carry;
        if (i < NB) { bbase[w * (NB + 1) + i] = excl; gcur[w * NB + i] = excl; }
        int tot = sm[255];
        __syncthreads();
        if (t == 0) carry += tot;
        __syncthreads();
    }
    if (t == 0) bbase[w * (NB + 1) + NB] = NEDGE;
}

// ---- distribute edges into bucket regions, packed (src<<8)|dst_local ----
__global__ void k_dist(const int* __restrict__ ei_at, const int* __restrict__ ei_ta,
                       int* __restrict__ gcur, unsigned* __restrict__ eb_at,
                       unsigned* __restrict__ eb_ta, int GD) {
    __shared__ int h[NB];
    __shared__ int bs[NB];
    bool wh = blockIdx.x >= GD;
    int blk = blockIdx.x - (wh ? GD : 0);
    const int* ei = wh ? ei_ta : ei_at;
    unsigned* eb = wh ? eb_ta : eb_at;
    for (int i = threadIdx.x; i < NB; i += 256) h[i] = 0;
    __syncthreads();
    long e0 = (long)blk * 256 + threadIdx.x;
    long stride = (long)GD * 256;
    for (long e = e0; e < NEDGE; e += stride)
        atomicAdd(&h[ei[NEDGE + e] >> 8], 1);
    __syncthreads();
    int* gc = gcur + (wh ? NB : 0);
    for (int i = threadIdx.x; i < NB; i += 256) {
        int c = h[i];
        bs[i] = c ? atomicAdd(&gc[i], c) : 0;
        h[i] = 0;
    }
    __syncthreads();
    for (long e = e0; e < NEDGE; e += stride) {
        int d = ei[NEDGE + e];
        int s = ei[e];
        int b = d >> 8;
        int r = atomicAdd(&h[b], 1);
        eb[bs[b] + r] = ((unsigned)s << 8) | (unsigned)(d & 255);
    }
}

// ---- one block per bucket: per-node degree, LDS scan -> rp, local col fill ----
__global__ void k_csrb(const unsigned* __restrict__ eb_at, const unsigned* __restrict__ eb_ta,
                       const int* __restrict__ bbase,
                       int* __restrict__ rp_tx, int* __restrict__ rp_ad,
                       int* __restrict__ col_at, int* __restrict__ col_ta) {
    __shared__ int deg[256];
    __shared__ int cur[256];
    __shared__ int sm[256];
    bool wh = blockIdx.x >= NB;
    int b = blockIdx.x - (wh ? NB : 0);
    const unsigned* eb = wh ? eb_ta : eb_at;
    int* rp  = wh ? rp_ad  : rp_tx;
    int* col = wh ? col_ta : col_at;
    const int* bb = bbase + (wh ? (NB + 1) : 0);
    int e0 = bb[b], e1 = bb[b + 1];
    int t = threadIdx.x;
    deg[t] = 0;
    __syncthreads();
    for (int e = e0 + t; e < e1; e += 256)
        atomicAdd(&deg[eb[e] & 255], 1);
    __syncthreads();
    int v = deg[t];
    sm[t] = v;
    __syncthreads();
    for (int off = 1; off < 256; off <<= 1) {
        int x = (t >= off) ? sm[t - off] : 0;
        __syncthreads();
        sm[t] += x;
        __syncthreads();
    }
    int excl = sm[t] - v;
    int node = b * 256 + t;
    if (node < 400000) rp[node] = e0 + excl;
    cur[t] = e0 + excl;
    __syncthreads();
    for (int e = e0 + t; e < e1; e += 256) {
        unsigned p = eb[e];
        int idx = atomicAdd(&cur[p & 255], 1);
        col[idx] = (int)(p >> 8);
    }
    if (t == 0 && b == 0) rp[400000] = NEDGE;
}

// ================= dense pre-transform (layer 1 only) =======================

template<int F>
__global__ void k_linear(const float* __restrict__ x, const float* __restrict__ w,
                         float* __restrict__ y, int n) {
    int i = blockIdx.x * 256 + threadIdx.x;
    if (i >= n) return;
    const float4* xr = (const float4*)(x + (size_t)i * F);
    float acc[HID];
#pragma unroll
    for (int j = 0; j < HID; ++j) acc[j] = 0.0f;
#pragma unroll
    for (int k4 = 0; k4 < F / 4; ++k4) {
        float4 xv = xr[k4];
        const float* wr = w + k4 * 4 * HID;
#pragma unroll
        for (int j = 0; j < HID; ++j) acc[j] = __builtin_fmaf(xv.x, wr[j], acc[j]);
#pragma unroll
        for (int j = 0; j < HID; ++j) acc[j] = __builtin_fmaf(xv.y, wr[HID + j], acc[j]);
#pragma unroll
        for (int j = 0; j < HID; ++j) acc[j] = __builtin_fmaf(xv.z, wr[2 * HID + j], acc[j]);
#pragma unroll
        for (int j = 0; j < HID; ++j) acc[j] = __builtin_fmaf(xv.w, wr[3 * HID + j], acc[j]);
    }
    float* yr = y + (size_t)i * HID;
#pragma unroll
    for (int j = 0; j < HID; j += 4) {
        float4 o = make_float4(acc[j], acc[j + 1], acc[j + 2], acc[j + 3]);
        *(float4*)(yr + j) = o;
    }
}

// ================= fused SAGE aggregation ===================================
template<int F, bool PRE, bool FINAL>
__global__ void k_agg(const int* __restrict__ rp, const int* __restrict__ col,
                      const float* __restrict__ src,
                      const float* xd,
                      const float* __restrict__ wl,
                      const float* __restrict__ w,
                      const float* __restrict__ b,
                      float* y,
                      const float* __restrict__ wo,
                      const float* __restrict__ bo,
                      int n) {
    int t = blockIdx.x * 256 + threadIdx.x;
    int g = t >> 5;
    int j = t & 31;
    if (g >= n) return;
    int p0 = rp[g], p1 = rp[g + 1];

    float acc = 0.0f;
    for (int k = p0; k < p1; k += 8) {
        int last = p1 - 1;
        int c1 = k + 1 < p1 ? k + 1 : last;
        int c2 = k + 2 < p1 ? k + 2 : last;
        int c3 = k + 3 < p1 ? k + 3 : last;
        int c4 = k + 4 < p1 ? k + 4 : last;
        int c5 = k + 5 < p1 ? k + 5 : last;
        int c6 = k + 6 < p1 ? k + 6 : last;
        int c7 = k + 7 < p1 ? k + 7 : last;
        int s0 = col[k],  s1 = col[c1], s2 = col[c2], s3 = col[c3];
        int s4 = col[c4], s5 = col[c5], s6 = col[c6], s7 = col[c7];
        float v0 = src[(size_t)s0 * HID + j];
        float v1 = src[(size_t)s1 * HID + j];
        float v2 = src[(size_t)s2 * HID + j];
        float v3 = src[(size_t)s3 * HID + j];
        float v4 = src[(size_t)s4 * HID + j];
        float v5 = src[(size_t)s5 * HID + j];
        float v6 = src[(size_t)s6 * HID + j];
        float v7 = src[(size_t)s7 * HID + j];
        acc += v0;
        acc += (k + 1 < p1) ? v1 : 0.0f;
        acc += (k + 2 < p1) ? v2 : 0.0f;
        acc += (k + 3 < p1) ? v3 : 0.0f;
        acc += (k + 4 < p1) ? v4 : 0.0f;
        acc += (k + 5 < p1) ? v5 : 0.0f;
        acc += (k + 6 < p1) ? v6 : 0.0f;
        acc += (k + 7 < p1) ? v7 : 0.0f;
    }
    float inv = 1.0f / fmaxf((float)(p1 - p0), 1.0f);
    float am = acc * inv;

    float h = b[j];
    if (PRE) {
        h += am;
    } else {
#pragma unroll
        for (int k = 0; k < 32; ++k)
            h = __builtin_fmaf(__shfl(am, k, 32), wl[k * HID + j], h);
    }

    const float* xr = xd + (size_t)g * F;
    float xv0 = xr[j];
    float xv1 = (F == 64) ? xr[32 + j] : 0.0f;
#pragma unroll
    for (int k = 0; k < 32; ++k) {
        h = __builtin_fmaf(__shfl(xv0, k, 32), w[k * HID + j], h);
        if (F == 64)
            h = __builtin_fmaf(__shfl(xv1, k, 32), w[(k + 32) * HID + j], h);
    }
    float v = h > 0.0f ? h : 0.0f;

    if (!FINAL) {
        y[(size_t)g * HID + j] = v;
    } else {
        float o0 = v * wo[j * 2 + 0];
        float o1 = v * wo[j * 2 + 1];
#pragma unroll
        for (int m = 16; m >= 1; m >>= 1) {
            o0 += __shfl_xor(o0, m, 32);
            o1 += __shfl_xor(o1, m, 32);
        }
        if (j == 0) {
            y[(size_t)g * 2 + 0] = o0 + bo[0];
            y[(size_t)g * 2 + 1] = o1 + bo[1];
        }
    }
}

// ============================================================================

extern "C" void kernel_launch(void* const* d_in, const int* in_sizes, int n_in,
                              void* d_out, int out_size, void* d_ws, size_t ws_size,
                              hipStream_t stream) {
    const float* x_addr  = (const float*)d_in[0];
    const float* x_tx    = (const float*)d_in[1];
    const int*   ei_at   = (const int*)d_in[2];
    const int*   ei_ta   = (const int*)d_in[3];
    const float* w1_tx_l = (const float*)d_in[4];  const float* b1_tx = (const float*)d_in[5];
    const float* w1_tx_r = (const float*)d_in[6];
    const float* w1_ad_l = (const float*)d_in[7];  const float* b1_ad = (const float*)d_in[8];
    const float* w1_ad_r = (const float*)d_in[9];
    const float* w2_tx_l = (const float*)d_in[10]; const float* b2_tx = (const float*)d_in[11];
    const float* w2_tx_r = (const float*)d_in[12];
    const float* w2_ad_l = (const float*)d_in[13]; const float* b2_ad = (const float*)d_in[14];
    const float* w2_ad_r = (const float*)d_in[15];
    // d_in[16..18] unused (w3_tx_*)
    const float* w3_ad_l = (const float*)d_in[19]; const float* b3_ad = (const float*)d_in[20];
    const float* w3_ad_r = (const float*)d_in[21];
    const float* w_out   = (const float*)d_in[22]; const float* b_out = (const float*)d_in[23];
    float* out = (float*)d_out;

    // ---- workspace carve ----
    char* base = (char*)d_ws;
    int* bcnt   = (int*)base;  base += (size_t)(2 * NB) * 4;
    int* bbase  = (int*)base;  base += (size_t)(2 * (NB + 1)) * 4;
    int* gcur   = (int*)base;  base += (size_t)(2 * NB) * 4;
    int* rp_tx  = (int*)base;  base += (size_t)(NTX + 1) * 4;
    int* rp_ad  = (int*)base;  base += (size_t)(NADDR + 1) * 4;
    int* col_at = (int*)base;  base += (size_t)NEDGE * 4;
    int* col_ta = (int*)base;  base += (size_t)NEDGE * 4;
    unsigned* eb_at = (unsigned*)base;  base += (size_t)NEDGE * 4;
    unsigned* eb_ta = (unsigned*)base;  base += (size_t)NEDGE * 4;
    base = (char*)(((size_t)base + 255) & ~(size_t)255);
    const size_t SLOT = (size_t)400000 * HID;
    float* S0 = (float*)base;   // pre scratch (layer 1)
    float* S1 = S0 + SLOT;      // tx
    float* S2 = S1 + SLOT;      // ad -> ad2 (in place)
    float* S3 = S2 + SLOT;      // tx2

    dim3 blk(256);
    int gN = cdiv_host(400000, 256);              // 1563
    int gG = cdiv_host((long)400000 * 32, 256);   // 50000
    const int GH = 96, GD = 192;

    // ---- bucketed CSR build (both edge types) ----
    hipMemsetAsync(bcnt, 0, (size_t)(2 * NB) * 4, stream);
    k_hist<<<2 * GH, blk, 0, stream>>>(ei_at + NEDGE, ei_ta + NEDGE, bcnt, GH);
    k_scan_nb<<<2, blk, 0, stream>>>(bcnt, bbase, gcur);
    k_dist<<<2 * GD, blk, 0, stream>>>(ei_at, ei_ta, gcur, eb_at, eb_ta, GD);
    k_csrb<<<2 * NB, blk, 0, stream>>>(eb_at, eb_ta, bbase, rp_tx, rp_ad, col_at, col_ta);

    // ---- layer 1: tx = relu(mean_at(x_addr@w1_tx_l) + x_tx@w1_tx_r + b1_tx) ----
    k_linear<FIN><<<gN, blk, 0, stream>>>(x_addr, w1_tx_l, S0, NADDR);
    k_agg<FIN, true, false><<<gG, blk, 0, stream>>>(rp_tx, col_at, S0, x_tx, nullptr,
                                                    w1_tx_r, b1_tx, S1, nullptr, nullptr, NTX);
    // ---- layer 1: ad ----
    k_linear<FIN><<<gN, blk, 0, stream>>>(x_tx, w1_ad_l, S0, NTX);
    k_agg<FIN, true, false><<<gG, blk, 0, stream>>>(rp_ad, col_ta, S0, x_addr, nullptr,
                                                    w1_ad_r, b1_ad, S2, nullptr, nullptr, NADDR);
    // ---- layer 2: tx2 -> S3 ----
    k_agg<HID, false, false><<<gG, blk, 0, stream>>>(rp_tx, col_at, S2, S1, w2_tx_l,
                                                     w2_tx_r, b2_tx, S3, nullptr, nullptr, NTX);
    // ---- layer 2: ad2 -> S2 in place ----
    k_agg<HID, false, false><<<gG, blk, 0, stream>>>(rp_ad, col_ta, S1, S2, w2_ad_l,
                                                     w2_ad_r, b2_ad, S2, nullptr, nullptr, NADDR);
    // ---- layer 3 + classifier -> out ----
    k_agg<HID, false, true><<<gG, blk, 0, stream>>>(rp_ad, col_ta, S3, S2, w3_ad_l,
                                                    w3_ad_r, b3_ad, out, w_out, b_out, NADDR);
}